// Round 14
// baseline (186.486 us; speedup 1.0000x reference)
//
#include <hip/hip_runtime.h>
#include <stdint.h>

namespace {

constexpr int Bb = 8, Ll = 6, Dd = 256, Pp = 1024;
constexpr float SCALE_Y = 14.285714285714286f * 1.4426950408889634f; // (1/0.07)*log2(e)
constexpr float M0y = 21.0f;   // > max |y| = 20.61
constexpr float LN2f = 0.6931471805599453f;

typedef __attribute__((ext_vector_type(4))) float floatx4;

// upper-triangular tile pairs (pt<=qt), encoded pt*16+qt
__device__ const int PAIRS[36] = {
  0x00,0x01,0x02,0x03,0x04,0x05,0x06,0x07,
  0x11,0x12,0x13,0x14,0x15,0x16,0x17,
  0x22,0x23,0x24,0x25,0x26,0x27,
  0x33,0x34,0x35,0x36,0x37,
  0x44,0x45,0x46,0x47,
  0x55,0x56,0x57,
  0x66,0x67,
  0x77
};

// ---------------- JAX threefry2x32 (key = (0, 42)), bit-exact ----------------
__device__ __forceinline__ uint32_t rotl32(uint32_t x, int n) {
  return (x << n) | (x >> (32 - n));
}
__device__ __forceinline__ void tf_round(uint32_t& x0, uint32_t& x1, int r) {
  x0 += x1; x1 = rotl32(x1, r); x1 ^= x0;
}
__device__ void threefry2x32(uint32_t x0, uint32_t x1, uint32_t& o0, uint32_t& o1) {
  const uint32_t k0 = 0u, k1 = 42u;
  const uint32_t k2 = k0 ^ k1 ^ 0x1BD11BDAu;
  x0 += k0; x1 += k1;
  tf_round(x0,x1,13); tf_round(x0,x1,15); tf_round(x0,x1,26); tf_round(x0,x1,6);
  x0 += k1; x1 += k2 + 1u;
  tf_round(x0,x1,17); tf_round(x0,x1,29); tf_round(x0,x1,16); tf_round(x0,x1,24);
  x0 += k2; x1 += k0 + 2u;
  tf_round(x0,x1,13); tf_round(x0,x1,15); tf_round(x0,x1,26); tf_round(x0,x1,6);
  x0 += k0; x1 += k1 + 3u;
  tf_round(x0,x1,17); tf_round(x0,x1,29); tf_round(x0,x1,16); tf_round(x0,x1,24);
  x0 += k1; x1 += k2 + 4u;
  tf_round(x0,x1,13); tf_round(x0,x1,15); tf_round(x0,x1,26); tf_round(x0,x1,6);
  x0 += k2; x1 += k0 + 5u;
  o0 = x0; o1 = x1;
}
__device__ float jax_u01(uint32_t idx) {
  const uint32_t HALF = (uint32_t)(Bb * Ll * Pp / 2); // 24576
  uint32_t o0, o1, bits;
  if (idx < HALF) { threefry2x32(idx, idx + HALF, o0, o1); bits = o0; }
  else            { threefry2x32(idx - HALF, idx, o0, o1); bits = o1; }
  return __uint_as_float((bits >> 9) | 0x3f800000u) - 1.0f;
}

// ---------------- OCP fp8 e4m3fn encode (RNE) / decode — software fallback ----
__device__ __forceinline__ uint32_t fp8e4m3_rne(float x) {
  uint32_t u = __float_as_uint(x);
  const uint32_t s = (u >> 24) & 0x80u;
  u &= 0x7FFFFFFFu;
  uint32_t code;
  if (u < 0x3C800000u) {                       // |x| < 2^-6: subnormal (step 2^-9)
    code = (uint32_t)__float2int_rn(__uint_as_float(u) * 512.0f);
  } else {
    const uint32_t r = (u + 0x7FFFFu + ((u >> 20) & 1u)) >> 20;    // RNE
    code = r - (120u << 3);                     // rebias 127->7
  }
  return s | code;
}
__device__ __forceinline__ float fp8e4m3_tof(uint32_t c) {
  const uint32_t e = (c >> 3) & 15u, m = c & 7u;
  float mag;
  if (e) mag = __uint_as_float(((e + 120u) << 23) | (m << 20));
  else   mag = (float)m * 0.001953125f;        // m * 2^-9
  return (c & 0x80u) ? -mag : mag;
}

// decode 4 packed fp8 bytes -> accumulate a[j]*b[j] into s (HW literal selectors)
__device__ __forceinline__ void fp8x4_dot(uint32_t a, uint32_t b, float& s) {
#if __has_builtin(__builtin_amdgcn_cvt_f32_fp8)
  s += __builtin_amdgcn_cvt_f32_fp8((int)a, 0) * __builtin_amdgcn_cvt_f32_fp8((int)b, 0);
  s += __builtin_amdgcn_cvt_f32_fp8((int)a, 1) * __builtin_amdgcn_cvt_f32_fp8((int)b, 1);
  s += __builtin_amdgcn_cvt_f32_fp8((int)a, 2) * __builtin_amdgcn_cvt_f32_fp8((int)b, 2);
  s += __builtin_amdgcn_cvt_f32_fp8((int)a, 3) * __builtin_amdgcn_cvt_f32_fp8((int)b, 3);
#else
  s += fp8e4m3_tof(a & 0xFF) * fp8e4m3_tof(b & 0xFF);
  s += fp8e4m3_tof((a >> 8) & 0xFF) * fp8e4m3_tof((b >> 8) & 0xFF);
  s += fp8e4m3_tof((a >> 16) & 0xFF) * fp8e4m3_tof((b >> 16) & 0xFF);
  s += fp8e4m3_tof((a >> 24) & 0xFF) * fp8e4m3_tof((b >> 24) & 0xFF);
#endif
}

// ---------------- fused prep kernel — norm MERGED into row-stats (r13) ---------
constexpr int NB_ROW = Bb * Pp / 4;       // 2048

__global__ void prep_k(const float* __restrict__ meta, const int* __restrict__ thing,
                       const int* __restrict__ label, uint8_t* __restrict__ wn,
                       int* __restrict__ qpos, int* __restrict__ negc,
                       int* __restrict__ qidx, int* __restrict__ Kv,
                       int* __restrict__ gatev, float* __restrict__ rowsum_g,
                       int* __restrict__ cnt2, float* __restrict__ out) {
  __shared__ int sK[256], sG[256];
  const int bid = blockIdx.x, t = threadIdx.x;

  if (bid < NB_ROW) {
    // ---- merged normalize(6 layers) + row stats: one wave per (b,p) ----
    const int wid = bid * 4 + (t >> 6);
    const int lane = t & 63;
    const int b = wid >> 10, p = wid & (Pp - 1);

    // -- normalize: 6 contiguous rows, ILP across layers --
    const float* mbase = meta + (size_t)wid * (Ll * Dd);
    float4 v[Ll];
    #pragma unroll
    for (int k = 0; k < Ll; ++k)
      v[k] = *(const float4*)(mbase + k * Dd + lane * 4);
    float ss[Ll];
    #pragma unroll
    for (int k = 0; k < Ll; ++k)
      ss[k] = v[k].x * v[k].x + v[k].y * v[k].y + v[k].z * v[k].z + v[k].w * v[k].w;
    #pragma unroll
    for (int m = 32; m; m >>= 1) {
      #pragma unroll
      for (int k = 0; k < Ll; ++k) ss[k] += __shfl_xor(ss[k], m, 64);
    }
    #pragma unroll
    for (int k = 0; k < Ll; ++k) {
      const float inv = 1.0f / fmaxf(sqrtf(ss[k]), 1e-12f);
      uint8_t* dst = wn + ((size_t)(b * Ll + k) * Pp + p) * Dd + lane * 4;
#if __has_builtin(__builtin_amdgcn_cvt_pk_fp8_f32)
      const int lo16 = __builtin_amdgcn_cvt_pk_fp8_f32(v[k].x * inv, v[k].y * inv, 0, false);
      const uint32_t packed =
          (uint32_t)__builtin_amdgcn_cvt_pk_fp8_f32(v[k].z * inv, v[k].w * inv, lo16, true);
#else
      const uint32_t packed = fp8e4m3_rne(v[k].x * inv)
                            | (fp8e4m3_rne(v[k].y * inv) << 8)
                            | (fp8e4m3_rne(v[k].z * inv) << 16)
                            | (fp8e4m3_rne(v[k].w * inv) << 24);
#endif
      *(uint32_t*)dst = packed;
    }

    // -- row stats (unchanged logic) --
    const int* lab = label + b * Pp;
    const int* th  = thing + b * Pp;
    const int myLab = lab[p];
    const bool myValid = (th[p] != 0);

    uint32_t posbits = 0;
    int cnt[16];
    int pc = 0, nc = 0, last = -1;
    #pragma unroll
    for (int c = 0; c < 16; ++c) {
      const int q = c * 64 + lane;
      const int lq = lab[q];
      const bool vq = (th[q] != 0);
      const bool same = (lq == myLab);
      const bool pos = myValid && vq && same && (q != p);
      const bool neg = myValid && vq && !same;
      uint64_t bp2 = __ballot(pos);
      uint64_t bn = __ballot(neg);
      if (pos) posbits |= (1u << c);
      cnt[c] = __popcll(bp2);
      pc += cnt[c];
      nc += __popcll(bn);
      if (bn) last = c * 64 + 63 - __clzll(bn);
    }
    int qsel[Ll];
    #pragma unroll
    for (int l = 0; l < Ll; ++l) qsel[l] = p;
    if (pc > 0) {
      for (int l = 0; l < Ll; ++l) {
        const float u = jax_u01((uint32_t)((b * Ll + l) * Pp + p));
        int r = (int)floorf(u * (float)pc);
        r = min(r, pc - 1);
        int base = 0;
        for (int c = 0; c < 16; ++c) {
          if (r < base + cnt[c]) {
            const bool mine = (posbits >> c) & 1u;
            uint64_t bm = __ballot(mine);
            uint64_t ltmask = (lane == 0) ? 0ull : (~0ull >> (64 - lane));
            int myrank = __popcll(bm & ltmask);
            bool hit = mine && (base + myrank == r);
            uint64_t hb = __ballot(hit);
            qsel[l] = c * 64 + (int)__builtin_ctzll(hb);
            break;
          }
          base += cnt[c];
        }
      }
    }
    if (lane == 0) {
      negc[wid] = nc;
      qidx[wid] = (last < 0) ? 0 : last;
      #pragma unroll
      for (int l = 0; l < Ll; ++l) qpos[(b * Ll + l) * Pp + p] = qsel[l];
    }
    return;
  }
  if (bid < NB_ROW + Bb) {
    // ---- batch stats ----
    const int b = bid - NB_ROW;
    int k = 0;
    for (int p = t; p < Pp; p += 256) k += (thing[b * Pp + p] != 0);
    int g = 0;
    if (t < 128) {
      int any = 0;
      for (int tt = 0; tt < 8; ++tt) any |= (thing[(b * 128 + t) * 8 + tt] != 0);
      g = any;
    }
    sK[t] = k; sG[t] = g;
    __syncthreads();
    for (int s = 128; s; s >>= 1) {
      if (t < s) { sK[t] += sK[t + s]; sG[t] += sG[t + s]; }
      __syncthreads();
    }
    if (t == 0) { Kv[b] = sK[0]; gatev[b] = (sG[0] >= 2) ? 1 : 0; }
    return;
  }
  if (bid < NB_ROW + Bb + 48) {
    // ---- zero rowsum_g (+ cnt2 in the first of these blocks) ----
    const int zb = bid - (NB_ROW + Bb);
    const int idx = zb * 256 + t;
    *(float4*)(rowsum_g + idx * 4) = (float4){0.f, 0.f, 0.f, 0.f};
    if (zb == 0 && t < 192) { cnt2[t] = 0; cnt2[t + 192] = 0; }   // 384 counters
    return;
  }
  if (t == 0) out[0] = 0.f;
}

// ---------------- fp8 MFMA Gram, ZERO-staging (direct-from-L2 fragments) -------
// r12 proved the barrier-drain chain (4 staged K-steps x vmcnt(0)) is ~60% of
// per-block time; r10/r11/r12 bracket the staging family at ~53 us. r14 drops
// LDS staging entirely (guide Common-mistake #7: don't stage what cache-fits —
// each (b,l) slab is 256 KB, 6 slabs/XCD = 1.5 MB, L2-resident): MFMA fragments
// are read DIRECTLY from global as 8B loads. Per thread: 6 base pointers
// (4 A-rows + 2 B-rows, + rq-dependent column offset), then 8 sub-steps x 6
// global_load_dwordx2 with compile-time offset immediates (sub*32). All loads
// independent -> compiler pipelines them under MFMAs; the K-phase has ZERO
// barriers, ZERO LDS, ZERO swizzle. LDS drops to ~5 KB (labels + reduction).
// Epilogue, protocol (RELAXED bump after vmcnt-drained atomics, last-arriver
// finalizes), and parallel finalize unchanged from r10/r13.
__global__ __launch_bounds__(512)
void gemmfinal_k(const uint8_t* __restrict__ wn,
                 const int* __restrict__ thing, const int* __restrict__ label,
                 const int* __restrict__ qpos, const int* __restrict__ qidx,
                 const int* __restrict__ negc, const int* __restrict__ Kv,
                 const int* __restrict__ gatev, float* __restrict__ rowsum_g,
                 int* __restrict__ cnt2, float* __restrict__ out) {
  __shared__ int labp_s[128], valp_s[128], labq_s[128], valq_s[128];
  __shared__ float rowsum_lds[128], colsum_lds[128];
  __shared__ int fin_s[2];
  __shared__ int fin_any;
  __shared__ float sb[512];

  const int t = threadIdx.x;
  const int bid = blockIdx.x;
  const int xcd = bid & 7;
  const int chunk = bid >> 3;          // 0..215
  const int bl = xcd + 8 * (chunk % 6);
  const int b = bl / Ll;
  const int pair = PAIRS[chunk / 6];
  const int pt = pair >> 4, qt = pair & 15;
  const bool diag = (pt == qt);
  const int p0 = pt * 128, q0 = qt * 128;
  const int blP = bl * Pp;

  if (t == 0) fin_any = 0;
  if (t < 128) {
    labp_s[t] = label[b * Pp + p0 + t];
    valp_s[t] = thing[b * Pp + p0 + t];
    labq_s[t] = label[b * Pp + q0 + t];
    valq_s[t] = thing[b * Pp + q0 + t];
    rowsum_lds[t] = 0.f;
    colsum_lds[t] = 0.f;
  }

  const uint8_t* Wbl = wn + (size_t)bl * Pp * Dd;
  const int lane = t & 63;
  const int w = t >> 6;                // 0..7
  const int wr = w >> 2, wc = w & 3;   // wave tile: rows wr*64, cols wc*32
  const int cq = lane & 15, rq = lane >> 4;

  // per-thread fragment base pointers: row base + rq-dependent column offset
  const int coff = (rq >> 1) * 16 + (rq & 1) * 8;   // byte offset within 64B group
  const uint8_t* arow[4];
  const uint8_t* brow[2];
  #pragma unroll
  for (int fi = 0; fi < 4; ++fi)
    arow[fi] = Wbl + (size_t)(p0 + wr * 64 + fi * 16 + cq) * Dd + coff;
  #pragma unroll
  for (int fj = 0; fj < 2; ++fj)
    brow[fj] = Wbl + (size_t)(q0 + wc * 32 + fj * 16 + cq) * Dd + coff;

  floatx4 acc[4][2];
  #pragma unroll
  for (int i = 0; i < 4; ++i)
    #pragma unroll
    for (int j = 0; j < 2; ++j) acc[i][j] = (floatx4){0.f, 0.f, 0.f, 0.f};

  // ---- K loop: 8 sub-steps, direct 8B loads from L2, no barriers, no LDS ----
  #pragma unroll
  for (int sub = 0; sub < 8; ++sub) {      // k = sub*32 .. +31; byte col += 32
    long long af[4], bfr[2];
    #pragma unroll
    for (int fi = 0; fi < 4; ++fi)
      af[fi] = *(const long long*)(arow[fi] + sub * 32);
    #pragma unroll
    for (int fj = 0; fj < 2; ++fj)
      bfr[fj] = *(const long long*)(brow[fj] + sub * 32);
    #pragma unroll
    for (int fi = 0; fi < 4; ++fi)
      #pragma unroll
      for (int fj = 0; fj < 2; ++fj)
        acc[fi][fj] = __builtin_amdgcn_mfma_f32_16x16x32_fp8_fp8(af[fi], bfr[fj],
                                                                 acc[fi][fj], 0, 0, 0);
  }

  __syncthreads();   // label preload visible for epilogue

  // ---- epilogue: masked exp sums, row-side + col-side ----
  int qlabv[2];
  float qvalf[2];
  float csum[2] = {0.f, 0.f};
  #pragma unroll
  for (int fj = 0; fj < 2; ++fj) {
    const int cl = wc * 32 + fj * 16 + cq;
    qlabv[fj] = labq_s[cl];
    qvalf[fj] = valq_s[cl] ? 1.f : 0.f;
  }
  #pragma unroll
  for (int fi = 0; fi < 4; ++fi) {
    #pragma unroll
    for (int reg = 0; reg < 4; ++reg) {
      const int rl = wr * 64 + fi * 16 + rq * 4 + reg;    // C row=(lane>>4)*4+reg
      const int rlab = labp_s[rl];
      const float rvalf = valp_s[rl] ? 1.f : 0.f;
      float rsum = 0.f;
      #pragma unroll
      for (int fj = 0; fj < 2; ++fj) {
        const float e = exp2f(fmaf(acc[fi][fj][reg], SCALE_Y, -M0y));
        const float negm = (qlabv[fj] != rlab) ? (qvalf[fj] * rvalf) : 0.f;
        const float term = negm * e;
        rsum += term;
        csum[fj] += term;
      }
      rsum += __shfl_xor(rsum, 1); rsum += __shfl_xor(rsum, 2);
      rsum += __shfl_xor(rsum, 4); rsum += __shfl_xor(rsum, 8);
      if (cq == 0) atomicAdd(&rowsum_lds[rl], rsum);
    }
  }
  if (!diag) {
    #pragma unroll
    for (int fj = 0; fj < 2; ++fj) {
      float c = csum[fj];
      c += __shfl_xor(c, 16); c += __shfl_xor(c, 32);
      if (rq == 0) atomicAdd(&colsum_lds[wc * 32 + fj * 16 + cq], c);
    }
  }
  __syncthreads();
  if (t < 128) {
    atomicAdd(&rowsum_g[blP + p0 + t], rowsum_lds[t]);
    if (!diag) atomicAdd(&rowsum_g[blP + q0 + t], colsum_lds[t]);
  }
  __syncthreads();   // vmcnt(0): device-scope rowsum atomics complete

  // ---- completion bump (RELAXED, no fences): last toucher finalizes ----
  if (t == 0) {
    const int n1 = __hip_atomic_fetch_add(&cnt2[bl * 8 + pt], 1,
                                          __ATOMIC_RELAXED, __HIP_MEMORY_SCOPE_AGENT);
    fin_s[0] = (n1 == 7);
    int f1 = 0;
    if (!diag) {
      const int n2 = __hip_atomic_fetch_add(&cnt2[bl * 8 + qt], 1,
                                            __ATOMIC_RELAXED, __HIP_MEMORY_SCOPE_AGENT);
      f1 = (n2 == 7);
    }
    fin_s[1] = f1;
    if (fin_s[0] | f1) fin_any = 1;
  }
  __syncthreads();

  if (!fin_any) return;   // ~89% of blocks: no finalize, no reduction barriers

  // ---- finalize completed range(s): quarter-row-per-thread parallel pass ----
  float accl = 0.f;
  if (gatev[b]) {
    const int Kb = Kv[b];
    const float invK = 1.f / (float)max(Kb, 1);
    const int qtr = t & 3;             // 64B quarter of the row
    const int rrow = t >> 2;           // 0..127
    #pragma unroll
    for (int fr = 0; fr < 2; ++fr) {
      if (!fin_s[fr]) continue;
      const int p = (fr ? qt : pt) * 128 + rrow;
      const int valid = thing[b * Pp + p];
      const int qp = qpos[blP + p];
      const int qi = qidx[b * Pp + p];
      const uint8_t* rp = Wbl + (size_t)p  * Dd + qtr * 64;
      const uint8_t* rq2 = Wbl + (size_t)qp * Dd + qtr * 64;
      const uint8_t* rx = Wbl + (size_t)qi * Dd + qtr * 64;
      float sp = 0.f, sl = 0.f;
      #pragma unroll
      for (int i = 0; i < 4; ++i) {
        const uint4 a4 = *(const uint4*)(rp + i * 16);
        const uint4 b4 = *(const uint4*)(rq2 + i * 16);
        const uint4 c4 = *(const uint4*)(rx + i * 16);
        fp8x4_dot(a4.x, b4.x, sp); fp8x4_dot(a4.y, b4.y, sp);
        fp8x4_dot(a4.z, b4.z, sp); fp8x4_dot(a4.w, b4.w, sp);
        fp8x4_dot(a4.x, c4.x, sl); fp8x4_dot(a4.y, c4.y, sl);
        fp8x4_dot(a4.z, c4.z, sl); fp8x4_dot(a4.w, c4.w, sl);
      }
      sp += __shfl_xor(sp, 1); sp += __shfl_xor(sp, 2);   // combine 4 quarters
      sl += __shfl_xor(sl, 1); sl += __shfl_xor(sl, 2);
      if (qtr == 0 && valid != 0) {
        const float yp = sp * SCALE_Y, yl = sl * SCALE_Y;
        const float rs = __hip_atomic_load(&rowsum_g[blP + p],
                                           __ATOMIC_RELAXED, __HIP_MEMORY_SCOPE_AGENT);
        const int nc = negc[b * Pp + p];
        const float pad = fmaxf((float)(Kb - 1 - nc), 0.f);
        const float tot = exp2f(yp - M0y) + rs + ((nc > 0) ? pad * exp2f(yl - M0y) : 0.f);
        accl += LN2f * (M0y + log2f(tot) - yp) * invK;
      }
    }
  }
  sb[t] = accl;
  __syncthreads();
  for (int s = 256; s; s >>= 1) {
    if (t < s) sb[t] += sb[t + s];
    __syncthreads();
  }
  if (t == 0 && sb[0] != 0.f) atomicAdd(out, sb[0]);
}

}  // namespace

extern "C" void kernel_launch(void* const* d_in, const int* in_sizes, int n_in,
                              void* d_out, int out_size, void* d_ws, size_t ws_size,
                              hipStream_t stream) {
  const float* meta = (const float*)d_in[0];
  const int* thing  = (const int*)d_in[1];
  const int* label  = (const int*)d_in[2];
  float* out = (float*)d_out;

  char* ws = (char*)d_ws;
  size_t off = 0;
  uint8_t* wn = (uint8_t*)(ws + off); off += (size_t)Bb * Ll * Pp * Dd;  // 12.6 MB fp8
  int* qpos  = (int*)(ws + off); off += (size_t)Bb * Ll * Pp * 4;
  int* negc  = (int*)(ws + off); off += (size_t)Bb * Pp * 4;
  int* qidx  = (int*)(ws + off); off += (size_t)Bb * Pp * 4;
  int* Kv    = (int*)(ws + off); off += 64;
  int* gatev = (int*)(ws + off); off += 64;
  float* rowsum_g = (float*)(ws + off); off += (size_t)Bb * Ll * Pp * 4;
  int* cnt2  = (int*)(ws + off); off += 384 * 4;   // 48 slabs x 8 row-ranges

  const int nb_prep = NB_ROW + Bb + 48 + 1;  // 2105
  prep_k<<<nb_prep, 256, 0, stream>>>(meta, thing, label, wn, qpos, negc, qidx,
                                      Kv, gatev, rowsum_g, cnt2, out);
  gemmfinal_k<<<8 * 6 * 36, 512, 0, stream>>>(wn, thing, label, qpos, qidx, negc,
                                              Kv, gatev, rowsum_g, cnt2, out);
}

// Round 15
// 143.445 us; speedup vs baseline: 1.3001x; 1.3001x over previous
//
#include <hip/hip_runtime.h>
#include <stdint.h>

namespace {

constexpr int Bb = 8, Ll = 6, Dd = 256, Pp = 1024;
constexpr float SCALE_Y = 14.285714285714286f * 1.4426950408889634f; // (1/0.07)*log2(e)
constexpr float M0y = 21.0f;   // > max |y| = 20.61
constexpr float LN2f = 0.6931471805599453f;

typedef __attribute__((ext_vector_type(4))) float floatx4;

// upper-triangular tile pairs (pt<=qt), encoded pt*16+qt
__device__ const int PAIRS[36] = {
  0x00,0x01,0x02,0x03,0x04,0x05,0x06,0x07,
  0x11,0x12,0x13,0x14,0x15,0x16,0x17,
  0x22,0x23,0x24,0x25,0x26,0x27,
  0x33,0x34,0x35,0x36,0x37,
  0x44,0x45,0x46,0x47,
  0x55,0x56,0x57,
  0x66,0x67,
  0x77
};

// async global->LDS DMA, 16B per lane; LDS dest = wave-uniform base + lane*16
__device__ __forceinline__ void async16(const void* g, void* l) {
  __builtin_amdgcn_global_load_lds(
      (const __attribute__((address_space(1))) void*)g,
      (__attribute__((address_space(3))) void*)l, 16, 0, 0);
}

// ---------------- JAX threefry2x32 (key = (0, 42)), bit-exact ----------------
__device__ __forceinline__ uint32_t rotl32(uint32_t x, int n) {
  return (x << n) | (x >> (32 - n));
}
__device__ __forceinline__ void tf_round(uint32_t& x0, uint32_t& x1, int r) {
  x0 += x1; x1 = rotl32(x1, r); x1 ^= x0;
}
__device__ void threefry2x32(uint32_t x0, uint32_t x1, uint32_t& o0, uint32_t& o1) {
  const uint32_t k0 = 0u, k1 = 42u;
  const uint32_t k2 = k0 ^ k1 ^ 0x1BD11BDAu;
  x0 += k0; x1 += k1;
  tf_round(x0,x1,13); tf_round(x0,x1,15); tf_round(x0,x1,26); tf_round(x0,x1,6);
  x0 += k1; x1 += k2 + 1u;
  tf_round(x0,x1,17); tf_round(x0,x1,29); tf_round(x0,x1,16); tf_round(x0,x1,24);
  x0 += k2; x1 += k0 + 2u;
  tf_round(x0,x1,13); tf_round(x0,x1,15); tf_round(x0,x1,26); tf_round(x0,x1,6);
  x0 += k0; x1 += k1 + 3u;
  tf_round(x0,x1,17); tf_round(x0,x1,29); tf_round(x0,x1,16); tf_round(x0,x1,24);
  x0 += k1; x1 += k2 + 4u;
  tf_round(x0,x1,13); tf_round(x0,x1,15); tf_round(x0,x1,26); tf_round(x0,x1,6);
  x0 += k2; x1 += k0 + 5u;
  o0 = x0; o1 = x1;
}
__device__ float jax_u01(uint32_t idx) {
  const uint32_t HALF = (uint32_t)(Bb * Ll * Pp / 2); // 24576
  uint32_t o0, o1, bits;
  if (idx < HALF) { threefry2x32(idx, idx + HALF, o0, o1); bits = o0; }
  else            { threefry2x32(idx - HALF, idx, o0, o1); bits = o1; }
  return __uint_as_float((bits >> 9) | 0x3f800000u) - 1.0f;
}

// ---------------- OCP fp8 e4m3fn encode (RNE) / decode — software fallback ----
__device__ __forceinline__ uint32_t fp8e4m3_rne(float x) {
  uint32_t u = __float_as_uint(x);
  const uint32_t s = (u >> 24) & 0x80u;
  u &= 0x7FFFFFFFu;
  uint32_t code;
  if (u < 0x3C800000u) {                       // |x| < 2^-6: subnormal (step 2^-9)
    code = (uint32_t)__float2int_rn(__uint_as_float(u) * 512.0f);
  } else {
    const uint32_t r = (u + 0x7FFFFu + ((u >> 20) & 1u)) >> 20;    // RNE
    code = r - (120u << 3);                     // rebias 127->7
  }
  return s | code;
}
__device__ __forceinline__ float fp8e4m3_tof(uint32_t c) {
  const uint32_t e = (c >> 3) & 15u, m = c & 7u;
  float mag;
  if (e) mag = __uint_as_float(((e + 120u) << 23) | (m << 20));
  else   mag = (float)m * 0.001953125f;        // m * 2^-9
  return (c & 0x80u) ? -mag : mag;
}

// decode 4 packed fp8 bytes -> accumulate a[j]*b[j] into s (HW literal selectors)
__device__ __forceinline__ void fp8x4_dot(uint32_t a, uint32_t b, float& s) {
#if __has_builtin(__builtin_amdgcn_cvt_f32_fp8)
  s += __builtin_amdgcn_cvt_f32_fp8((int)a, 0) * __builtin_amdgcn_cvt_f32_fp8((int)b, 0);
  s += __builtin_amdgcn_cvt_f32_fp8((int)a, 1) * __builtin_amdgcn_cvt_f32_fp8((int)b, 1);
  s += __builtin_amdgcn_cvt_f32_fp8((int)a, 2) * __builtin_amdgcn_cvt_f32_fp8((int)b, 2);
  s += __builtin_amdgcn_cvt_f32_fp8((int)a, 3) * __builtin_amdgcn_cvt_f32_fp8((int)b, 3);
#else
  s += fp8e4m3_tof(a & 0xFF) * fp8e4m3_tof(b & 0xFF);
  s += fp8e4m3_tof((a >> 8) & 0xFF) * fp8e4m3_tof((b >> 8) & 0xFF);
  s += fp8e4m3_tof((a >> 16) & 0xFF) * fp8e4m3_tof((b >> 16) & 0xFF);
  s += fp8e4m3_tof((a >> 24) & 0xFF) * fp8e4m3_tof((b >> 24) & 0xFF);
#endif
}

// ---------------- fused prep kernel — norm MERGED into row-stats (r13) ---------
constexpr int NB_ROW = Bb * Pp / 4;       // 2048

__global__ void prep_k(const float* __restrict__ meta, const int* __restrict__ thing,
                       const int* __restrict__ label, uint8_t* __restrict__ wn,
                       int* __restrict__ qpos, int* __restrict__ negc,
                       int* __restrict__ qidx, int* __restrict__ Kv,
                       int* __restrict__ gatev, float* __restrict__ rowsum_g,
                       int* __restrict__ cnt2, float* __restrict__ out) {
  __shared__ int sK[256], sG[256];
  const int bid = blockIdx.x, t = threadIdx.x;

  if (bid < NB_ROW) {
    // ---- merged normalize(6 layers) + row stats: one wave per (b,p) ----
    const int wid = bid * 4 + (t >> 6);
    const int lane = t & 63;
    const int b = wid >> 10, p = wid & (Pp - 1);

    // -- normalize: 6 contiguous rows, ILP across layers --
    const float* mbase = meta + (size_t)wid * (Ll * Dd);
    float4 v[Ll];
    #pragma unroll
    for (int k = 0; k < Ll; ++k)
      v[k] = *(const float4*)(mbase + k * Dd + lane * 4);
    float ss[Ll];
    #pragma unroll
    for (int k = 0; k < Ll; ++k)
      ss[k] = v[k].x * v[k].x + v[k].y * v[k].y + v[k].z * v[k].z + v[k].w * v[k].w;
    #pragma unroll
    for (int m = 32; m; m >>= 1) {
      #pragma unroll
      for (int k = 0; k < Ll; ++k) ss[k] += __shfl_xor(ss[k], m, 64);
    }
    #pragma unroll
    for (int k = 0; k < Ll; ++k) {
      const float inv = 1.0f / fmaxf(sqrtf(ss[k]), 1e-12f);
      uint8_t* dst = wn + ((size_t)(b * Ll + k) * Pp + p) * Dd + lane * 4;
#if __has_builtin(__builtin_amdgcn_cvt_pk_fp8_f32)
      const int lo16 = __builtin_amdgcn_cvt_pk_fp8_f32(v[k].x * inv, v[k].y * inv, 0, false);
      const uint32_t packed =
          (uint32_t)__builtin_amdgcn_cvt_pk_fp8_f32(v[k].z * inv, v[k].w * inv, lo16, true);
#else
      const uint32_t packed = fp8e4m3_rne(v[k].x * inv)
                            | (fp8e4m3_rne(v[k].y * inv) << 8)
                            | (fp8e4m3_rne(v[k].z * inv) << 16)
                            | (fp8e4m3_rne(v[k].w * inv) << 24);
#endif
      *(uint32_t*)dst = packed;
    }

    // -- row stats (unchanged logic) --
    const int* lab = label + b * Pp;
    const int* th  = thing + b * Pp;
    const int myLab = lab[p];
    const bool myValid = (th[p] != 0);

    uint32_t posbits = 0;
    int cnt[16];
    int pc = 0, nc = 0, last = -1;
    #pragma unroll
    for (int c = 0; c < 16; ++c) {
      const int q = c * 64 + lane;
      const int lq = lab[q];
      const bool vq = (th[q] != 0);
      const bool same = (lq == myLab);
      const bool pos = myValid && vq && same && (q != p);
      const bool neg = myValid && vq && !same;
      uint64_t bp2 = __ballot(pos);
      uint64_t bn = __ballot(neg);
      if (pos) posbits |= (1u << c);
      cnt[c] = __popcll(bp2);
      pc += cnt[c];
      nc += __popcll(bn);
      if (bn) last = c * 64 + 63 - __clzll(bn);
    }
    int qsel[Ll];
    #pragma unroll
    for (int l = 0; l < Ll; ++l) qsel[l] = p;
    if (pc > 0) {
      for (int l = 0; l < Ll; ++l) {
        const float u = jax_u01((uint32_t)((b * Ll + l) * Pp + p));
        int r = (int)floorf(u * (float)pc);
        r = min(r, pc - 1);
        int base = 0;
        for (int c = 0; c < 16; ++c) {
          if (r < base + cnt[c]) {
            const bool mine = (posbits >> c) & 1u;
            uint64_t bm = __ballot(mine);
            uint64_t ltmask = (lane == 0) ? 0ull : (~0ull >> (64 - lane));
            int myrank = __popcll(bm & ltmask);
            bool hit = mine && (base + myrank == r);
            uint64_t hb = __ballot(hit);
            qsel[l] = c * 64 + (int)__builtin_ctzll(hb);
            break;
          }
          base += cnt[c];
        }
      }
    }
    if (lane == 0) {
      negc[wid] = nc;
      qidx[wid] = (last < 0) ? 0 : last;
      #pragma unroll
      for (int l = 0; l < Ll; ++l) qpos[(b * Ll + l) * Pp + p] = qsel[l];
    }
    return;
  }
  if (bid < NB_ROW + Bb) {
    // ---- batch stats ----
    const int b = bid - NB_ROW;
    int k = 0;
    for (int p = t; p < Pp; p += 256) k += (thing[b * Pp + p] != 0);
    int g = 0;
    if (t < 128) {
      int any = 0;
      for (int tt = 0; tt < 8; ++tt) any |= (thing[(b * 128 + t) * 8 + tt] != 0);
      g = any;
    }
    sK[t] = k; sG[t] = g;
    __syncthreads();
    for (int s = 128; s; s >>= 1) {
      if (t < s) { sK[t] += sK[t + s]; sG[t] += sG[t + s]; }
      __syncthreads();
    }
    if (t == 0) { Kv[b] = sK[0]; gatev[b] = (sG[0] >= 2) ? 1 : 0; }
    return;
  }
  if (bid < NB_ROW + Bb + 48) {
    // ---- zero rowsum_g (+ cnt2 in the first of these blocks) ----
    const int zb = bid - (NB_ROW + Bb);
    const int idx = zb * 256 + t;
    *(float4*)(rowsum_g + idx * 4) = (float4){0.f, 0.f, 0.f, 0.f};
    if (zb == 0 && t < 192) { cnt2[t] = 0; cnt2[t + 192] = 0; }   // 384 counters
    return;
  }
  if (t == 0) out[0] = 0.f;
}

// ---------------- fp8 MFMA Gram + tail-fused finalize — r10/r13 structure ------
// Design-space closure: r10/r13 (1728 x 1-tile, BK=64 dbuf staging, 512 thr)
// = 53 us; r11 2-tiles/block = 66.6; r12 full-K burst = 66.8; r14 zero-staging
// direct-L2 = 99 (8B x 256B-stride loads destroy coalescing — LDS staging IS
// the coalescer). This is the measured optimum of the decomposition.
// r15 micro-trim: drop the dead kt=3 barrier (no staging follows; epilogue
// reads only registers + prologue-ordered LDS). 5 -> 4 barriers/tile.
// Protocol (RELAXED bump after vmcnt-drained atomics, last-arriver finalizes)
// unchanged from r6/r8.
__global__ __launch_bounds__(512)
void gemmfinal_k(const uint8_t* __restrict__ wn,
                 const int* __restrict__ thing, const int* __restrict__ label,
                 const int* __restrict__ qpos, const int* __restrict__ qidx,
                 const int* __restrict__ negc, const int* __restrict__ Kv,
                 const int* __restrict__ gatev, float* __restrict__ rowsum_g,
                 int* __restrict__ cnt2, float* __restrict__ out) {
  __shared__ __align__(16) uint8_t As[2 * 128 * 64];  // 16 KB ping-pong
  __shared__ __align__(16) uint8_t Bs[2 * 128 * 64];
  __shared__ int labp_s[128], valp_s[128], labq_s[128], valq_s[128];
  __shared__ float rowsum_lds[128], colsum_lds[128];
  __shared__ int fin_s[2];
  __shared__ int fin_any;
  __shared__ float sb[512];

  const int t = threadIdx.x;
  const int bid = blockIdx.x;
  const int xcd = bid & 7;
  const int chunk = bid >> 3;          // 0..215
  const int bl = xcd + 8 * (chunk % 6);
  const int b = bl / Ll;
  const int pair = PAIRS[chunk / 6];
  const int pt = pair >> 4, qt = pair & 15;
  const bool diag = (pt == qt);
  const int p0 = pt * 128, q0 = qt * 128;
  const int blP = bl * Pp;

  if (t == 0) fin_any = 0;
  if (t < 128) {
    labp_s[t] = label[b * Pp + p0 + t];
    valp_s[t] = thing[b * Pp + p0 + t];
    labq_s[t] = label[b * Pp + q0 + t];
    valq_s[t] = thing[b * Pp + q0 + t];
    rowsum_lds[t] = 0.f;
    colsum_lds[t] = 0.f;
  }

  const uint8_t* Wbl = wn + (size_t)bl * Pp * Dd;
  const int lane = t & 63;
  const int w = t >> 6;                // 0..7
  const int wr = w >> 2, wc = w & 3;   // wave tile: rows wr*64, cols wc*32
  const int cq = lane & 15, rq = lane >> 4;
  const int wbase16 = (t & ~63) * 16;  // wave-uniform lds byte base per 64-lane group

  floatx4 acc[4][2];
  #pragma unroll
  for (int i = 0; i < 4; ++i)
    #pragma unroll
    for (int j = 0; j < 2; ++j) acc[i][j] = (floatx4){0.f, 0.f, 0.f, 0.f};

  // stage one 128x64B K-tile: exactly 1 chunk/thread/buffer (512 thr = 512 chunks)
  auto STAGE = [&](int bsel, int kt) {
    const int k0 = kt * 64;
    const int row = t >> 2, sp2 = t & 3;   // 16B chunk id: row, physical slot
    const int sl = sp2 ^ ((row >> 1) & 3); // XOR swizzle: logical k-slot stored here
    async16(Wbl + (size_t)(p0 + row) * Dd + k0 + sl * 16,
            As + bsel * 8192 + wbase16);
    if (!diag)
      async16(Wbl + (size_t)(q0 + row) * Dd + k0 + sl * 16,
              Bs + bsel * 8192 + wbase16);
  };

  STAGE(0, 0);
  __syncthreads();   // tile 0 visible + label preload ordered

  const uint8_t* Bbase0 = diag ? As : Bs;
  for (int kt = 0; kt < 4; ++kt) {
    const int bsel = kt & 1;
    if (kt < 3) STAGE(bsel ^ 1, kt + 1);    // prefetch flies under MFMAs
    const uint8_t* Ab = As + bsel * 8192;
    const uint8_t* Bb2 = Bbase0 + bsel * 8192;
    #pragma unroll
    for (int sub = 0; sub < 2; ++sub) {      // k = kt*64 + sub*32 .. +31
      const int Lw = sub * 2 + (rq >> 1);    // logical 16B chunk within 64B row
      const int off8 = (rq & 1) * 8;
      long long af[4], bfr[2];
      #pragma unroll
      for (int fi = 0; fi < 4; ++fi) {
        const int row = wr * 64 + fi * 16 + cq;
        af[fi] = *(const long long*)(Ab + row * 64 + (Lw ^ ((row >> 1) & 3)) * 16 + off8);
      }
      #pragma unroll
      for (int fj = 0; fj < 2; ++fj) {
        const int row = wc * 32 + fj * 16 + cq;
        bfr[fj] = *(const long long*)(Bb2 + row * 64 + (Lw ^ ((row >> 1) & 3)) * 16 + off8);
      }
      #pragma unroll
      for (int fi = 0; fi < 4; ++fi)
        #pragma unroll
        for (int fj = 0; fj < 2; ++fj)
          acc[fi][fj] = __builtin_amdgcn_mfma_f32_16x16x32_fp8_fp8(af[fi], bfr[fj],
                                                                   acc[fi][fj], 0, 0, 0);
    }
    if (kt < 3) __syncthreads();   // kt=3: no staging follows -> barrier is dead
  }

  // ---- epilogue: masked exp sums, row-side + col-side ----
  int qlabv[2];
  float qvalf[2];
  float csum[2] = {0.f, 0.f};
  #pragma unroll
  for (int fj = 0; fj < 2; ++fj) {
    const int cl = wc * 32 + fj * 16 + cq;
    qlabv[fj] = labq_s[cl];
    qvalf[fj] = valq_s[cl] ? 1.f : 0.f;
  }
  #pragma unroll
  for (int fi = 0; fi < 4; ++fi) {
    #pragma unroll
    for (int reg = 0; reg < 4; ++reg) {
      const int rl = wr * 64 + fi * 16 + rq * 4 + reg;    // C row=(lane>>4)*4+reg
      const int rlab = labp_s[rl];
      const float rvalf = valp_s[rl] ? 1.f : 0.f;
      float rsum = 0.f;
      #pragma unroll
      for (int fj = 0; fj < 2; ++fj) {
        const float e = exp2f(fmaf(acc[fi][fj][reg], SCALE_Y, -M0y));
        const float negm = (qlabv[fj] != rlab) ? (qvalf[fj] * rvalf) : 0.f;
        const float term = negm * e;
        rsum += term;
        csum[fj] += term;
      }
      rsum += __shfl_xor(rsum, 1); rsum += __shfl_xor(rsum, 2);
      rsum += __shfl_xor(rsum, 4); rsum += __shfl_xor(rsum, 8);
      if (cq == 0) atomicAdd(&rowsum_lds[rl], rsum);
    }
  }
  if (!diag) {
    #pragma unroll
    for (int fj = 0; fj < 2; ++fj) {
      float c = csum[fj];
      c += __shfl_xor(c, 16); c += __shfl_xor(c, 32);
      if (rq == 0) atomicAdd(&colsum_lds[wc * 32 + fj * 16 + cq], c);
    }
  }
  __syncthreads();
  if (t < 128) {
    atomicAdd(&rowsum_g[blP + p0 + t], rowsum_lds[t]);
    if (!diag) atomicAdd(&rowsum_g[blP + q0 + t], colsum_lds[t]);
  }
  __syncthreads();   // vmcnt(0): device-scope rowsum atomics complete

  // ---- completion bump (RELAXED, no fences): last toucher finalizes ----
  if (t == 0) {
    const int n1 = __hip_atomic_fetch_add(&cnt2[bl * 8 + pt], 1,
                                          __ATOMIC_RELAXED, __HIP_MEMORY_SCOPE_AGENT);
    fin_s[0] = (n1 == 7);
    int f1 = 0;
    if (!diag) {
      const int n2 = __hip_atomic_fetch_add(&cnt2[bl * 8 + qt], 1,
                                            __ATOMIC_RELAXED, __HIP_MEMORY_SCOPE_AGENT);
      f1 = (n2 == 7);
    }
    fin_s[1] = f1;
    if (fin_s[0] | f1) fin_any = 1;
  }
  __syncthreads();

  if (!fin_any) return;   // ~89% of blocks: no finalize, no reduction barriers

  // ---- finalize completed range(s): quarter-row-per-thread parallel pass ----
  float accl = 0.f;
  if (gatev[b]) {
    const int Kb = Kv[b];
    const float invK = 1.f / (float)max(Kb, 1);
    const int qtr = t & 3;             // 64B quarter of the row
    const int rrow = t >> 2;           // 0..127
    #pragma unroll
    for (int fr = 0; fr < 2; ++fr) {
      if (!fin_s[fr]) continue;
      const int p = (fr ? qt : pt) * 128 + rrow;
      const int valid = thing[b * Pp + p];
      const int qp = qpos[blP + p];
      const int qi = qidx[b * Pp + p];
      const uint8_t* rp = Wbl + (size_t)p  * Dd + qtr * 64;
      const uint8_t* rq2 = Wbl + (size_t)qp * Dd + qtr * 64;
      const uint8_t* rx = Wbl + (size_t)qi * Dd + qtr * 64;
      float sp = 0.f, sl = 0.f;
      #pragma unroll
      for (int i = 0; i < 4; ++i) {
        const uint4 a4 = *(const uint4*)(rp + i * 16);
        const uint4 b4 = *(const uint4*)(rq2 + i * 16);
        const uint4 c4 = *(const uint4*)(rx + i * 16);
        fp8x4_dot(a4.x, b4.x, sp); fp8x4_dot(a4.y, b4.y, sp);
        fp8x4_dot(a4.z, b4.z, sp); fp8x4_dot(a4.w, b4.w, sp);
        fp8x4_dot(a4.x, c4.x, sl); fp8x4_dot(a4.y, c4.y, sl);
        fp8x4_dot(a4.z, c4.z, sl); fp8x4_dot(a4.w, c4.w, sl);
      }
      sp += __shfl_xor(sp, 1); sp += __shfl_xor(sp, 2);   // combine 4 quarters
      sl += __shfl_xor(sl, 1); sl += __shfl_xor(sl, 2);
      if (qtr == 0 && valid != 0) {
        const float yp = sp * SCALE_Y, yl = sl * SCALE_Y;
        const float rs = __hip_atomic_load(&rowsum_g[blP + p],
                                           __ATOMIC_RELAXED, __HIP_MEMORY_SCOPE_AGENT);
        const int nc = negc[b * Pp + p];
        const float pad = fmaxf((float)(Kb - 1 - nc), 0.f);
        const float tot = exp2f(yp - M0y) + rs + ((nc > 0) ? pad * exp2f(yl - M0y) : 0.f);
        accl += LN2f * (M0y + log2f(tot) - yp) * invK;
      }
    }
  }
  sb[t] = accl;
  __syncthreads();
  for (int s = 256; s; s >>= 1) {
    if (t < s) sb[t] += sb[t + s];
    __syncthreads();
  }
  if (t == 0 && sb[0] != 0.f) atomicAdd(out, sb[0]);
}

}  // namespace

extern "C" void kernel_launch(void* const* d_in, const int* in_sizes, int n_in,
                              void* d_out, int out_size, void* d_ws, size_t ws_size,
                              hipStream_t stream) {
  const float* meta = (const float*)d_in[0];
  const int* thing  = (const int*)d_in[1];
  const int* label  = (const int*)d_in[2];
  float* out = (float*)d_out;

  char* ws = (char*)d_ws;
  size_t off = 0;
  uint8_t* wn = (uint8_t*)(ws + off); off += (size_t)Bb * Ll * Pp * Dd;  // 12.6 MB fp8
  int* qpos  = (int*)(ws + off); off += (size_t)Bb * Ll * Pp * 4;
  int* negc  = (int*)(ws + off); off += (size_t)Bb * Pp * 4;
  int* qidx  = (int*)(ws + off); off += (size_t)Bb * Pp * 4;
  int* Kv    = (int*)(ws + off); off += 64;
  int* gatev = (int*)(ws + off); off += 64;
  float* rowsum_g = (float*)(ws + off); off += (size_t)Bb * Ll * Pp * 4;
  int* cnt2  = (int*)(ws + off); off += 384 * 4;   // 48 slabs x 8 row-ranges

  const int nb_prep = NB_ROW + Bb + 48 + 1;  // 2105
  prep_k<<<nb_prep, 256, 0, stream>>>(meta, thing, label, wn, qpos, negc, qidx,
                                      Kv, gatev, rowsum_g, cnt2, out);
  gemmfinal_k<<<8 * 6 * 36, 512, 0, stream>>>(wn, thing, label, qpos, qidx, negc,
                                              Kv, gatev, rowsum_g, cnt2, out);
}